// Round 1
// baseline (1240.039 us; speedup 1.0000x reference)
//
#include <hip/hip_runtime.h>

#define D 64
#define SLOPE 0.2f
#define BN_EPS 1e-5f

// ---------------------------------------------------------------------------
// deg[dst] += 1 per edge
__global__ void k_degree(const int* __restrict__ dst, float* __restrict__ deg, int E) {
    for (int e = blockIdx.x * blockDim.x + threadIdx.x; e < E; e += gridDim.x * blockDim.x)
        atomicAdd(&deg[dst[e]], 1.0f);
}

// deg -> rsqrt(deg + 1)   (self-loop)
__global__ void k_dinv(float* __restrict__ deg, int N) {
    for (int i = blockIdx.x * blockDim.x + threadIdx.x; i < N; i += gridDim.x * blockDim.x)
        deg[i] = rsqrtf(deg[i] + 1.0f);
}

// ---------------------------------------------------------------------------
// xw = x @ W ; agg = xw * dinv^2 + b    (W staged in LDS, 4 rows per block-iter)
__global__ void k_gemm_agg(const float* __restrict__ x, const float* __restrict__ W,
                           const float* __restrict__ b, const float* __restrict__ dinv,
                           float* __restrict__ xw, float* __restrict__ agg, int N) {
    __shared__ float Wl[D * D];
    for (int i = threadIdx.x; i < D * D; i += blockDim.x) Wl[i] = W[i];
    __syncthreads();

    const int col = threadIdx.x & 63;
    const int rib = threadIdx.x >> 6;              // row-in-block 0..3
    const float bc = b[col];

    for (int row = blockIdx.x * 4 + rib; row < N; row += gridDim.x * 4) {
        const float* xr = x + (size_t)row * D;
        float acc = 0.0f;
#pragma unroll
        for (int k = 0; k < D; ++k)
            acc = fmaf(xr[k], Wl[k * D + col], acc);
        const float di = dinv[row];
        xw[(size_t)row * D + col]  = acc;
        agg[(size_t)row * D + col] = acc * (di * di) + bc;
    }
}

// ---------------------------------------------------------------------------
// one wave per edge: agg[dst][*] += xw[src][*] * dinv[src]*dinv[dst]
__global__ void k_edge(const int* __restrict__ src, const int* __restrict__ dst,
                       const float* __restrict__ dinv, const float* __restrict__ xw,
                       float* __restrict__ agg, int E) {
    const int lane = threadIdx.x & 63;
    const int wib  = threadIdx.x >> 6;             // wave in block
    const int wpb  = blockDim.x >> 6;
    const int wstride = gridDim.x * wpb;
    for (int e = blockIdx.x * wpb + wib; e < E; e += wstride) {
        const int s = src[e];
        const int d = dst[e];
        const float w = dinv[s] * dinv[d];
        const float v = xw[(size_t)s * D + lane] * w;
        atomicAdd(&agg[(size_t)d * D + lane], v);
    }
}

// ---------------------------------------------------------------------------
// LeakyReLU on the fly; per-column sum and sum-of-squares -> stats[0:64], stats[64:128]
__global__ void k_stats(const float* __restrict__ agg, float* __restrict__ stats, int total) {
    const int tid = threadIdx.x;
    float s1 = 0.0f, s2 = 0.0f;
    for (int i = blockIdx.x * blockDim.x + tid; i < total; i += gridDim.x * blockDim.x) {
        float a = agg[i];
        float h = a > 0.0f ? a : SLOPE * a;
        s1 += h;
        s2 += h * h;
    }
    __shared__ float l1[256], l2[256];
    l1[tid] = s1; l2[tid] = s2;
    __syncthreads();
    if (tid < 64) {
        s1 = l1[tid] + l1[tid + 64] + l1[tid + 128] + l1[tid + 192];
        s2 = l2[tid] + l2[tid + 64] + l2[tid + 128] + l2[tid + 192];
        atomicAdd(&stats[tid], s1);
        atomicAdd(&stats[64 + tid], s2);
    }
}

// ---------------------------------------------------------------------------
// fold gamma/beta/mu/var into scale+shift  (64 threads)
__global__ void k_finalize(const float* __restrict__ stats, const float* __restrict__ gamma,
                           const float* __restrict__ beta, float* __restrict__ ss, float invN) {
    const int t = threadIdx.x;
    const float mu  = stats[t] * invN;
    const float var = stats[64 + t] * invN - mu * mu;
    const float sc  = gamma[t] * rsqrtf(var + BN_EPS);
    ss[t]      = sc;
    ss[64 + t] = beta[t] - mu * sc;
}

// ---------------------------------------------------------------------------
// out = scale[col] * LeakyReLU(agg) + shift[col]
__global__ void k_normalize(const float* __restrict__ agg, const float* __restrict__ ss,
                            float* __restrict__ out, int total) {
    const int col = threadIdx.x & 63;              // stride multiple of 64 keeps col fixed
    const float sc = ss[col];
    const float sh = ss[64 + col];
    for (int i = blockIdx.x * blockDim.x + threadIdx.x; i < total; i += gridDim.x * blockDim.x) {
        float a = agg[i];
        float h = a > 0.0f ? a : SLOPE * a;
        out[i] = sc * h + sh;
    }
}

// ---------------------------------------------------------------------------
extern "C" void kernel_launch(void* const* d_in, const int* in_sizes, int n_in,
                              void* d_out, int out_size, void* d_ws, size_t ws_size,
                              hipStream_t stream) {
    const float* x0     = (const float*)d_in[0];
    const int*   ei     = (const int*)d_in[1];
    const float* Ws     = (const float*)d_in[2];
    const float* bs     = (const float*)d_in[3];
    const float* gammas = (const float*)d_in[4];
    const float* betas  = (const float*)d_in[5];

    const int N = in_sizes[0] / D;
    const int E = in_sizes[1] / 2;
    const int L = in_sizes[2] / (D * D);

    float* ws = (float*)d_ws;
    // layout (floats): [deg/dinv: N][pad][stats: L*128][ss: 128][pad][xw: N*D][agg: N*D]
    size_t off_stats = ((size_t)N + 255) & ~(size_t)255;
    size_t off_ss    = off_stats + (size_t)L * 128;
    size_t off_xw    = (off_ss + 128 + 255) & ~(size_t)255;
    size_t off_agg   = off_xw + (size_t)N * D;

    float* deg   = ws;
    float* stats = ws + off_stats;
    float* ss    = ws + off_ss;
    float* xw    = ws + off_xw;
    float* agg   = ws + off_agg;
    float* out   = (float*)d_out;

    const int* srcp = ei;
    const int* dstp = ei + E;

    // zero deg + stats (+ss region, harmless) once per call
    hipMemsetAsync(d_ws, 0, off_xw * sizeof(float), stream);

    k_degree<<<1024, 256, 0, stream>>>(dstp, deg, E);
    k_dinv<<<512, 256, 0, stream>>>(deg, N);

    const float* xin = x0;
    const float invN = 1.0f / (float)N;
    for (int l = 0; l < L; ++l) {
        k_gemm_agg<<<1024, 256, 0, stream>>>(xin, Ws + (size_t)l * D * D, bs + (size_t)l * D,
                                             deg, xw, agg, N);
        k_edge<<<2048, 256, 0, stream>>>(srcp, dstp, deg, xw, agg, E);
        k_stats<<<1024, 256, 0, stream>>>(agg, stats + (size_t)l * 128, N * D);
        k_finalize<<<1, 64, 0, stream>>>(stats + (size_t)l * 128, gammas + (size_t)l * D,
                                         betas + (size_t)l * D, ss, invN);
        k_normalize<<<1024, 256, 0, stream>>>(agg, ss, out, N * D);
        xin = out;   // d_out doubles as the x buffer for the next layer
    }
}

// Round 2
// 642.742 us; speedup vs baseline: 1.9293x; 1.9293x over previous
//
#include <hip/hip_runtime.h>

#define D 64
#define SLOPE 0.2f
#define BN_EPS 1e-5f

// ---------------------------------------------------------------------------
// CSR build: in-degree count
__global__ void k_count(const int* __restrict__ dst, int* __restrict__ cnt, int E) {
    for (int e = blockIdx.x * blockDim.x + threadIdx.x; e < E; e += gridDim.x * blockDim.x)
        atomicAdd(&cnt[dst[e]], 1);
}

__global__ void k_dinv(const int* __restrict__ cnt, float* __restrict__ dinv, int N) {
    for (int i = blockIdx.x * blockDim.x + threadIdx.x; i < N; i += gridDim.x * blockDim.x)
        dinv[i] = rsqrtf((float)cnt[i] + 1.0f);
}

// block-local exclusive scan (256/block); bsum[b] = block total
__global__ void k_scan1(const int* __restrict__ cnt, int* __restrict__ rp,
                        int* __restrict__ bsum, int N) {
    __shared__ int l[256];
    const int t = threadIdx.x;
    const int i = blockIdx.x * 256 + t;
    const int v = (i < N) ? cnt[i] : 0;
    l[t] = v;
    __syncthreads();
    for (int off = 1; off < 256; off <<= 1) {
        int x = l[t];
        if (t >= off) x += l[t - off];
        __syncthreads();
        l[t] = x;
        __syncthreads();
    }
    if (i < N) rp[i] = l[t] - v;              // block-local exclusive
    if (t == 255) bsum[blockIdx.x] = l[255];  // block total
}

// single-block exclusive scan of block sums (B <= 512)
__global__ void k_scan2(int* __restrict__ bsum, int* __restrict__ rp, int B, int E, int N) {
    __shared__ int l[512];
    const int t = threadIdx.x;
    const int v = (t < B) ? bsum[t] : 0;
    l[t] = v;
    __syncthreads();
    for (int off = 1; off < 512; off <<= 1) {
        int x = l[t];
        if (t >= off) x += l[t - off];
        __syncthreads();
        l[t] = x;
        __syncthreads();
    }
    if (t < B) bsum[t] = l[t] - v;
    if (t == 0) rp[N] = E;
}

__global__ void k_scan3(int* __restrict__ rp, const int* __restrict__ bsum, int N) {
    const int i = blockIdx.x * blockDim.x + threadIdx.x;
    if (i < N) rp[i] += bsum[i >> 8];
}

// colbuf[rp[d] + cur[d]++] = src(e)
__global__ void k_scatter(const int* __restrict__ src, const int* __restrict__ dst,
                          const int* __restrict__ rp, int* __restrict__ cur,
                          int* __restrict__ colbuf, int E) {
    for (int e = blockIdx.x * blockDim.x + threadIdx.x; e < E; e += gridDim.x * blockDim.x) {
        const int d = dst[e];
        const int pos = rp[d] + atomicAdd(&cur[d], 1);
        colbuf[pos] = src[e];
    }
}

// ---------------------------------------------------------------------------
// y[row] = ((AFFINE? sc*x+sh : x) @ W) * dinv[row]
// one wave per row: coalesced row load + shfl broadcast; W staged in LDS
template <bool AFFINE>
__global__ void k_gemm(const float* __restrict__ x, const float* __restrict__ W,
                       const float* __restrict__ ss, const float* __restrict__ dinv,
                       float* __restrict__ y, int N) {
    __shared__ float Wl[D * D];
    for (int i = threadIdx.x; i < D * D; i += blockDim.x) Wl[i] = W[i];
    __syncthreads();

    const int lane = threadIdx.x & 63;
    const int wib  = threadIdx.x >> 6;
    float sc = 1.0f, sh = 0.0f;
    if (AFFINE) { sc = ss[lane]; sh = ss[64 + lane]; }

    for (int row = blockIdx.x * 4 + wib; row < N; row += gridDim.x * 4) {
        float xo = x[(size_t)row * D + lane];
        if (AFFINE) xo = fmaf(sc, xo, sh);
        float acc = 0.0f;
#pragma unroll
        for (int k = 0; k < D; ++k) {
            const float xk = __shfl(xo, k, 64);
            acc = fmaf(xk, Wl[k * D + lane], acc);
        }
        y[(size_t)row * D + lane] = acc * dinv[row];
    }
}

// ---------------------------------------------------------------------------
// pull aggregation + LeakyReLU + fused BN stats
// h[n] = LeakyReLU(dinv[n]*(y[n] + sum_{s in in(n)} y[s]) + b)
__global__ void k_pull(const int* __restrict__ rp, const int* __restrict__ colbuf,
                       const float* __restrict__ y, const float* __restrict__ dinv,
                       const float* __restrict__ b, float* __restrict__ h,
                       float* __restrict__ stats, int N) {
    const int lane = threadIdx.x & 63;
    const int wib  = threadIdx.x >> 6;
    const float bc = b[lane];
    float s1 = 0.0f, s2 = 0.0f;

    for (int n = blockIdx.x * 4 + wib; n < N; n += gridDim.x * 4) {
        const int start = rp[n];
        const int end   = rp[n + 1];
        float acc0 = y[(size_t)n * D + lane];   // self term
        float acc1 = 0.0f, acc2 = 0.0f, acc3 = 0.0f;
        for (int j = start; j < end; j += 64) {
            const int rem = end - j;
            const int cn  = rem < 64 ? rem : 64;
            const int ci  = (lane < cn) ? colbuf[j + lane] : 0;
            int t = 0;
            for (; t + 4 <= cn; t += 4) {
                const int i0 = __shfl(ci, t, 64);
                const int i1 = __shfl(ci, t + 1, 64);
                const int i2 = __shfl(ci, t + 2, 64);
                const int i3 = __shfl(ci, t + 3, 64);
                acc0 += y[(size_t)i0 * D + lane];
                acc1 += y[(size_t)i1 * D + lane];
                acc2 += y[(size_t)i2 * D + lane];
                acc3 += y[(size_t)i3 * D + lane];
            }
            for (; t < cn; ++t) {
                const int i0 = __shfl(ci, t, 64);
                acc0 += y[(size_t)i0 * D + lane];
            }
        }
        const float v  = fmaf(dinv[n], (acc0 + acc1) + (acc2 + acc3), bc);
        const float hv = v > 0.0f ? v : SLOPE * v;
        h[(size_t)n * D + lane] = hv;
        s1 += hv;
        s2 += hv * hv;
    }

    __shared__ float l1[256], l2[256];
    l1[threadIdx.x] = s1;
    l2[threadIdx.x] = s2;
    __syncthreads();
    if (threadIdx.x < 64) {
        const float a = l1[threadIdx.x] + l1[threadIdx.x + 64] + l1[threadIdx.x + 128] + l1[threadIdx.x + 192];
        const float c = l2[threadIdx.x] + l2[threadIdx.x + 64] + l2[threadIdx.x + 128] + l2[threadIdx.x + 192];
        atomicAdd(&stats[threadIdx.x], a);
        atomicAdd(&stats[64 + threadIdx.x], c);
    }
}

// ---------------------------------------------------------------------------
__global__ void k_finalize(const float* __restrict__ stats, const float* __restrict__ gamma,
                           const float* __restrict__ beta, float* __restrict__ ss, float invN) {
    const int t = threadIdx.x;
    const float mu  = stats[t] * invN;
    const float var = stats[64 + t] * invN - mu * mu;
    const float sc  = gamma[t] * rsqrtf(var + BN_EPS);
    ss[t]      = sc;
    ss[64 + t] = beta[t] - mu * sc;
}

// final output only: out = sc*h + sh
__global__ void k_normalize(const float* __restrict__ h, const float* __restrict__ ss,
                            float* __restrict__ out, int total) {
    const int col = threadIdx.x & 63;
    const float sc = ss[col];
    const float sh = ss[64 + col];
    for (int i = blockIdx.x * blockDim.x + threadIdx.x; i < total; i += gridDim.x * blockDim.x)
        out[i] = fmaf(sc, h[i], sh);
}

// ---------------------------------------------------------------------------
extern "C" void kernel_launch(void* const* d_in, const int* in_sizes, int n_in,
                              void* d_out, int out_size, void* d_ws, size_t ws_size,
                              hipStream_t stream) {
    const float* x0     = (const float*)d_in[0];
    const int*   ei     = (const int*)d_in[1];
    const float* Ws     = (const float*)d_in[2];
    const float* bs     = (const float*)d_in[3];
    const float* gammas = (const float*)d_in[4];
    const float* betas  = (const float*)d_in[5];

    const int N = in_sizes[0] / D;
    const int E = in_sizes[1] / 2;
    const int L = in_sizes[2] / (D * D);

    const int* srcp = ei;
    const int* dstp = ei + E;

    // workspace layout (4-byte units), zero region first & contiguous
    char* wsb = (char*)d_ws;
    size_t o = 0;
    auto alloc = [&](size_t elems) { size_t r = o; o += (elems + 255) & ~(size_t)255; return r; };
    const size_t o_cnt   = alloc((size_t)N);          // int, zeroed
    const size_t o_cur   = alloc((size_t)N);          // int, zeroed
    const size_t o_stats = alloc((size_t)L * 128);    // float, zeroed
    const size_t zero_end = o;
    const size_t o_ss    = alloc((size_t)L * 128);    // float
    const size_t o_dinv  = alloc((size_t)N);          // float
    const size_t o_rp    = alloc((size_t)N + 1);      // int
    const size_t o_bsum  = alloc(512);                // int
    const size_t o_col   = alloc((size_t)E);          // int
    const size_t o_y     = alloc((size_t)N * D);      // float
    const size_t o_h     = alloc((size_t)N * D);      // float

    int*   cnt   = (int*)(wsb + o_cnt * 4);
    int*   cur   = (int*)(wsb + o_cur * 4);
    float* stats = (float*)(wsb + o_stats * 4);
    float* ss    = (float*)(wsb + o_ss * 4);
    float* dinv  = (float*)(wsb + o_dinv * 4);
    int*   rp    = (int*)(wsb + o_rp * 4);
    int*   bsum  = (int*)(wsb + o_bsum * 4);
    int*   col   = (int*)(wsb + o_col * 4);
    float* y     = (float*)(wsb + o_y * 4);
    float* h     = (float*)(wsb + o_h * 4);
    float* out   = (float*)d_out;

    hipMemsetAsync(d_ws, 0, zero_end * 4, stream);

    // CSR build
    k_count<<<1024, 256, 0, stream>>>(dstp, cnt, E);
    k_dinv<<<512, 256, 0, stream>>>(cnt, dinv, N);
    const int B = (N + 255) / 256;
    k_scan1<<<B, 256, 0, stream>>>(cnt, rp, bsum, N);
    k_scan2<<<1, 512, 0, stream>>>(bsum, rp, B, E, N);
    k_scan3<<<B, 256, 0, stream>>>(rp, bsum, N);
    k_scatter<<<1024, 256, 0, stream>>>(srcp, dstp, rp, cur, col, E);

    const float invN = 1.0f / (float)N;
    const float* xin = x0;
    for (int l = 0; l < L; ++l) {
        const float* Wl = Ws + (size_t)l * D * D;
        const float* bl = bs + (size_t)l * D;
        if (l == 0)
            k_gemm<false><<<1024, 256, 0, stream>>>(xin, Wl, nullptr, dinv, y, N);
        else
            k_gemm<true><<<1024, 256, 0, stream>>>(xin, Wl, ss + (size_t)(l - 1) * 128, dinv, y, N);
        k_pull<<<2048, 256, 0, stream>>>(rp, col, y, dinv, bl, h, stats + (size_t)l * 128, N);
        k_finalize<<<1, 64, 0, stream>>>(stats + (size_t)l * 128, gammas + (size_t)l * D,
                                         betas + (size_t)l * D, ss + (size_t)l * 128, invN);
        xin = h;
    }
    k_normalize<<<1024, 256, 0, stream>>>(h, ss + (size_t)(L - 1) * 128, out, N * D);
}